// Round 4
// baseline (1588.773 us; speedup 1.0000x reference)
//
#include <hip/hip_runtime.h>

// ---------- ws layout (float offsets) ----------
enum : int {
  WT1 = 0,          // [27][64]   conv1 weights transposed (cin*9+tap, cout)
  WT2 = 1728,       // [576][64]
  WT3 = 38592,      // [576][64]
  T1  = 75456,      // [9216][64] conv1 out
  T2  = 665280,     // [9216][64] conv2 out
  FEAT= 1255104,    // [9216][64] conv3 out
  PREDP=1844928,    // [3][147456] pre-refine pred planes
  FLAGP=2287296,    // [147456]
  WS_END = 2434752  // 9.74 MB
};

#define QTOT 147456

// ---------- prep: conv weight transpose (f32 in, f32 out) ----------
__global__ __launch_bounds__(256) void prep_k(
    const float* __restrict__ ew1, const float* __restrict__ ew2,
    const float* __restrict__ ew3, float* __restrict__ ws)
{
  int t = blockIdx.x * 256 + threadIdx.x;
  if (t < 1728){ int co=t/27,  r=t-co*27;  ws[WT1 + r*64 + co] = ew1[t]; return; } t -= 1728;
  if (t < 36864){ int co=t/576, r=t-co*576; ws[WT2 + r*64 + co] = ew2[t]; return; } t -= 36864;
  if (t < 36864){ int co=t/576, r=t-co*576; ws[WT3 + r*64 + co] = ew3[t]; return; }
}

// ---------- conv1: 3 -> 64, relu ----------
__global__ __launch_bounds__(256) void conv1_k(const float* __restrict__ lr, const float* __restrict__ wt1,
                                               const float* __restrict__ b1, float* __restrict__ out)
{
  int t  = threadIdx.x;
  int px = blockIdx.x * 4 + (t >> 6);
  int co = t & 63;
  int y = px / 96, x = px - y * 96;
  float acc = b1[co];
  #pragma unroll
  for (int dy = -1; dy <= 1; ++dy){
    int ny = y + dy; if (ny < 0 || ny > 95) continue;
    #pragma unroll
    for (int dx = -1; dx <= 1; ++dx){
      int nx = x + dx; if (nx < 0 || nx > 95) continue;
      int tap = (dy+1)*3 + (dx+1);
      #pragma unroll
      for (int ci = 0; ci < 3; ++ci)
        acc += lr[ci*9216 + ny*96 + nx] * wt1[(ci*9 + tap)*64 + co];
    }
  }
  out[px*64 + co] = fmaxf(acc, 0.f);
}

// ---------- conv 64->64 (generic, optional relu) ----------
__global__ __launch_bounds__(256) void conv64_k(const float* __restrict__ in, const float* __restrict__ wt,
                                                const float* __restrict__ bias, float* __restrict__ out, int relu)
{
  int t  = threadIdx.x;
  int px = blockIdx.x * 16 + (t >> 4);
  int co = (t & 15) * 4;
  int y = px / 96, x = px - y * 96;
  float4 acc = *(const float4*)(bias + co);
  #pragma unroll
  for (int dy = -1; dy <= 1; ++dy){
    int ny = y + dy; if (ny < 0 || ny > 95) continue;
    #pragma unroll
    for (int dx = -1; dx <= 1; ++dx){
      int nx = x + dx; if (nx < 0 || nx > 95) continue;
      int tap = (dy+1)*3 + (dx+1);
      const float* ip = in + (ny*96 + nx)*64;
      const float* wp = wt + tap*64 + co;
      #pragma unroll 4
      for (int c4 = 0; c4 < 16; ++c4){
        float4 iv = *(const float4*)(ip + c4*4);
        float4 w0 = *(const float4*)(wp + (c4*4+0)*576);
        float4 w1 = *(const float4*)(wp + (c4*4+1)*576);
        float4 w2 = *(const float4*)(wp + (c4*4+2)*576);
        float4 w3 = *(const float4*)(wp + (c4*4+3)*576);
        acc.x += iv.x*w0.x + iv.y*w1.x + iv.z*w2.x + iv.w*w3.x;
        acc.y += iv.x*w0.y + iv.y*w1.y + iv.z*w2.y + iv.w*w3.y;
        acc.z += iv.x*w0.z + iv.y*w1.z + iv.z*w2.z + iv.w*w3.z;
        acc.w += iv.x*w0.w + iv.y*w1.w + iv.z*w2.w + iv.w*w3.w;
      }
    }
  }
  if (relu){
    acc.x = fmaxf(acc.x, 0.f); acc.y = fmaxf(acc.y, 0.f);
    acc.z = fmaxf(acc.z, 0.f); acc.w = fmaxf(acc.w, 0.f);
  }
  *(float4*)(out + px*64 + co) = acc;
}

// ---------- dense layer helper: [64 q] x [K -> 256], relu, into stride-260 LDS ----------
template<int SRC_STRIDE>
__device__ __forceinline__ void dense256(const float* src, float* dst,
                                         const float* __restrict__ w, const float* __restrict__ b,
                                         int t, int k4n)
{
  int qg = t >> 6, cob = t & 63, co = cob * 4;
  float4 bb = *(const float4*)(b + co);
  float4 acc[16];
  #pragma unroll
  for (int i = 0; i < 16; ++i) acc[i] = bb;
  for (int k4 = 0; k4 < k4n; ++k4){
    float4 xx[16];
    #pragma unroll
    for (int i = 0; i < 16; ++i)
      xx[i] = *(const float4*)(src + (qg*16 + i)*SRC_STRIDE + k4*4);
    #pragma unroll
    for (int kk = 0; kk < 4; ++kk){
      float4 wv = *(const float4*)(w + (k4*4 + kk)*256 + co);
      #pragma unroll
      for (int i = 0; i < 16; ++i){
        float xv = (kk==0) ? xx[i].x : (kk==1) ? xx[i].y : (kk==2) ? xx[i].z : xx[i].w;
        acc[i].x += xv*wv.x; acc[i].y += xv*wv.y; acc[i].z += xv*wv.z; acc[i].w += xv*wv.w;
      }
    }
  }
  #pragma unroll
  for (int i = 0; i < 16; ++i){
    float4 r;
    r.x = fmaxf(acc[i].x, 0.f); r.y = fmaxf(acc[i].y, 0.f);
    r.z = fmaxf(acc[i].z, 0.f); r.w = fmaxf(acc[i].w, 0.f);
    *(float4*)(dst + (qg*16 + i)*260 + co) = r;
  }
}

// ---------- fused per-64-query MLP ----------
// static LDS: 38336 floats = 153,344 B (<= 160 KiB/CU on gfx950)
__global__ __launch_bounds__(256, 1) void mlp_k(float* __restrict__ ws,
    const float* __restrict__ lr, const float* __restrict__ coord, const float* __restrict__ cell,
    const float* __restrict__ wh1, const float* __restrict__ bh1,
    const float* __restrict__ wh2, const float* __restrict__ bh2,
    const float* __restrict__ wh3, const float* __restrict__ bh3,
    const float* __restrict__ wh4, const float* __restrict__ bh4,
    const float* __restrict__ wl1, const float* __restrict__ bl1,
    const float* __restrict__ wl2, const float* __restrict__ bl2,
    const float* __restrict__ wc1, const float* __restrict__ bc1,
    const float* __restrict__ wc2, const float* __restrict__ bc2,
    float* __restrict__ dout)
{
  __shared__ float smem[38336];
  float (*inp)[72] = (float (*)[72])smem;            // 4608
  float* haf = smem + 4608;                          // [64][260] = 16640
  float* hbf = smem + 21248;                         // [64][260] = 16640
  float* fl  = smem + 37888;                         // 64
  float* plv = smem + 37952;                         // [64][3]
  float* gsv = smem + 38144;                         // [64][3]  (total 38336 floats)
  const float* feat = ws + FEAT;
  const int t  = threadIdx.x;
  const int q0 = blockIdx.x * 64;

  // ---- gather: build inp[64][68] ----
  {
    int q = t >> 2, part = t & 3;
    int gq = q0 + q;
    float cy = coord[gq*2 + 0];
    float cx = coord[gq*2 + 1];
    // np: floor((c + 1.0) * 0.5 * h), clip 0..h-1
    int iy = (int)floorf(((cy + 1.f) * 0.5f) * 96.f); iy = iy < 0 ? 0 : (iy > 95 ? 95 : iy);
    int ix = (int)floorf(((cx + 1.f) * 0.5f) * 96.f); ix = ix < 0 ? 0 : (ix > 95 ? 95 : ix);
    const float* fp = feat + (iy*96 + ix)*64 + part*16;
    *(float4*)&inp[q][part*16 + 0]  = *(const float4*)(fp + 0);
    *(float4*)&inp[q][part*16 + 4]  = *(const float4*)(fp + 4);
    *(float4*)&inp[q][part*16 + 8]  = *(const float4*)(fp + 8);
    *(float4*)&inp[q][part*16 + 12] = *(const float4*)(fp + 12);
    if (part == 0){
      float fy = -1.f + (2.f*(float)iy + 1.f) / 96.f;
      float fx = -1.f + (2.f*(float)ix + 1.f) / 96.f;
      inp[q][64] = (cy - fy) * 96.f;
      inp[q][65] = (cx - fx) * 96.f;
      inp[q][66] = cell[gq*2 + 0] * 96.f;
      inp[q][67] = cell[gq*2 + 1] * 96.f;
      inp[q][68] = 0.f; inp[q][69] = 0.f; inp[q][70] = 0.f; inp[q][71] = 0.f;
    }
  }
  __syncthreads();

  // ---- classifier hidden (into haf) ----
  {
    int q = t >> 2, j0 = (t & 3) * 16;
    float a[16];
    #pragma unroll
    for (int j = 0; j < 16; ++j) a[j] = bc1[j0 + j];
    for (int k = 0; k < 68; ++k){
      float xv = inp[q][k];
      #pragma unroll
      for (int j = 0; j < 16; ++j) a[j] += xv * wc1[k*64 + j0 + j];
    }
    #pragma unroll
    for (int j = 0; j < 16; ++j) haf[q*260 + j0 + j] = fmaxf(a[j], 0.f);
  }
  __syncthreads();
  // ---- logits + flag ----
  if (t < 64){
    float l0 = bc2[0], l1 = bc2[1];
    for (int j = 0; j < 64; ++j){ float v = haf[t*260 + j]; l0 += v*wc2[j*2]; l1 += v*wc2[j*2+1]; }
    float f = (l1 > l0) ? 1.f : 0.f;
    fl[t] = f;
    ws[FLAGP + q0 + t] = f;
    dout[3*QTOT + q0 + t] = f;
  }
  __syncthreads();

  // ---- light hidden (into hbf) ----
  {
    int q = t >> 2, j0 = (t & 3) * 16;
    float a[16];
    #pragma unroll
    for (int j = 0; j < 16; ++j) a[j] = bl1[j0 + j];
    for (int k = 0; k < 68; ++k){
      float xv = inp[q][k];
      #pragma unroll
      for (int j = 0; j < 16; ++j) a[j] += xv * wl1[k*64 + j0 + j];
    }
    #pragma unroll
    for (int j = 0; j < 16; ++j) hbf[q*260 + j0 + j] = fmaxf(a[j], 0.f);
  }
  __syncthreads();
  // ---- light out + grid_sample ----
  if (t < 64){
    float o0 = bl2[0], o1 = bl2[1], o2 = bl2[2];
    for (int j = 0; j < 64; ++j){
      float v = hbf[t*260 + j];
      o0 += v*wl2[j*3]; o1 += v*wl2[j*3+1]; o2 += v*wl2[j*3+2];
    }
    int gq = q0 + t;
    float cy = coord[gq*2], cx = coord[gq*2 + 1];
    // np: clip((c + 1.0) * h / 2.0 - 0.5, 0, h-1)
    float fy = fminf(fmaxf((cy + 1.f) * 96.f / 2.f - 0.5f, 0.f), 95.f);
    float fx = fminf(fmaxf((cx + 1.f) * 96.f / 2.f - 0.5f, 0.f), 95.f);
    float y0f = floorf(fy), x0f = floorf(fx);
    float wy = fy - y0f, wx = fx - x0f;
    int y0 = (int)y0f, x0 = (int)x0f;
    int y1 = y0 + 1 > 95 ? 95 : y0 + 1;
    int x1 = x0 + 1 > 95 ? 95 : x0 + 1;
    float oo[3] = {o0, o1, o2};
    #pragma unroll
    for (int c = 0; c < 3; ++c){
      const float* lp = lr + c*9216;
      float v00 = lp[y0*96 + x0], v01 = lp[y0*96 + x1];
      float v10 = lp[y1*96 + x0], v11 = lp[y1*96 + x1];
      float v = v00*(1.f-wy)*(1.f-wx) + v01*(1.f-wy)*wx + v10*wy*(1.f-wx) + v11*wy*wx;
      gsv[t*3 + c] = v;
      plv[t*3 + c] = oo[c] + v;
    }
  }
  __syncthreads();

  // ---- heavy MLP ----
  dense256<72 >(&inp[0][0], haf, wh1, bh1, t, 17);  // 68 -> 256
  __syncthreads();
  dense256<260>(haf,        hbf, wh2, bh2, t, 64);  // 256 -> 256
  __syncthreads();
  dense256<260>(hbf,        haf, wh3, bh3, t, 64);  // 256 -> 256
  __syncthreads();

  // ---- final layer + select + store pre-refine pred ----
  if (t < 64){
    float a0 = bh4[0], a1 = bh4[1], a2 = bh4[2];
    for (int k = 0; k < 256; ++k){
      float v = haf[t*260 + k];
      a0 += v*wh4[k*3]; a1 += v*wh4[k*3+1]; a2 += v*wh4[k*3+2];
    }
    int gq = q0 + t;
    bool hard = fl[t] > 0.5f;
    float p0 = hard ? (a0 + gsv[t*3+0]) : plv[t*3+0];
    float p1 = hard ? (a1 + gsv[t*3+1]) : plv[t*3+1];
    float p2 = hard ? (a2 + gsv[t*3+2]) : plv[t*3+2];
    ws[PREDP + 0*QTOT + gq] = p0;
    ws[PREDP + 1*QTOT + gq] = p1;
    ws[PREDP + 2*QTOT + gq] = p2;
  }
}

// ---------- refinement + f32 store ----------
__global__ __launch_bounds__(256) void refine_k(const float* __restrict__ ws, float* __restrict__ dout)
{
  int q = blockIdx.x * 256 + threadIdx.x;
  const float* predp = ws + PREDP;
  const float* flagp = ws + FLAGP;
  int y = q / 384, x = q - y*384;
  float p0 = predp[q], p1 = predp[QTOT + q], p2 = predp[2*QTOT + q];
  if (y > 0 && y < 383 && x > 0 && x < 383 && flagp[q] == 0.f){
    float fs = 0.f, s0 = 0.f, s1 = 0.f, s2 = 0.f;
    #pragma unroll
    for (int dy = -1; dy <= 1; ++dy){
      #pragma unroll
      for (int dx = -1; dx <= 1; ++dx){
        int nq = q + dy*384 + dx;
        fs += flagp[nq];
        s0 += predp[nq]; s1 += predp[QTOT + nq]; s2 += predp[2*QTOT + nq];
      }
    }
    if (fs > 0.5f){ p0 = s0 / 9.f; p1 = s1 / 9.f; p2 = s2 / 9.f; }
  }
  dout[q*3 + 0] = p0;
  dout[q*3 + 1] = p1;
  dout[q*3 + 2] = p2;
}

extern "C" void kernel_launch(void* const* d_in, const int* in_sizes, int n_in,
                              void* d_out, int out_size, void* d_ws, size_t ws_size,
                              hipStream_t stream)
{
  const float* lr    = (const float*)d_in[0];
  const float* coord = (const float*)d_in[1];
  const float* cell  = (const float*)d_in[2];
  const float* ew1 = (const float*)d_in[3];  const float* eb1 = (const float*)d_in[4];
  const float* ew2 = (const float*)d_in[5];  const float* eb2 = (const float*)d_in[6];
  const float* ew3 = (const float*)d_in[7];  const float* eb3 = (const float*)d_in[8];
  const float* wh1 = (const float*)d_in[9];  const float* bh1 = (const float*)d_in[10];
  const float* wh2 = (const float*)d_in[11]; const float* bh2 = (const float*)d_in[12];
  const float* wh3 = (const float*)d_in[13]; const float* bh3 = (const float*)d_in[14];
  const float* wh4 = (const float*)d_in[15]; const float* bh4 = (const float*)d_in[16];
  const float* wl1 = (const float*)d_in[17]; const float* bl1 = (const float*)d_in[18];
  const float* wl2 = (const float*)d_in[19]; const float* bl2 = (const float*)d_in[20];
  const float* wc1 = (const float*)d_in[21]; const float* bc1 = (const float*)d_in[22];
  const float* wc2 = (const float*)d_in[23]; const float* bc2 = (const float*)d_in[24];
  float* ws  = (float*)d_ws;
  float* out = (float*)d_out;

  prep_k<<<295, 256, 0, stream>>>(ew1, ew2, ew3, ws);
  conv1_k<<<2304, 256, 0, stream>>>(lr, ws + WT1, eb1, ws + T1);
  conv64_k<<<576, 256, 0, stream>>>(ws + T1, ws + WT2, eb2, ws + T2, 1);
  conv64_k<<<576, 256, 0, stream>>>(ws + T2, ws + WT3, eb3, ws + FEAT, 0);
  mlp_k<<<2304, 256, 0, stream>>>(ws, lr, coord, cell,
                                  wh1, bh1, wh2, bh2, wh3, bh3, wh4, bh4,
                                  wl1, bl1, wl2, bl2, wc1, bc1, wc2, bc2, out);
  refine_k<<<576, 256, 0, stream>>>(ws, out);
}

// Round 5
// 536.615 us; speedup vs baseline: 2.9607x; 2.9607x over previous
//
#include <hip/hip_runtime.h>

typedef unsigned short u16;
typedef __attribute__((ext_vector_type(8))) short bf16x8;
typedef __attribute__((ext_vector_type(4))) float f32x4;

// ---------- ws layout (float offsets) ----------
enum : int {
  WT1 = 0,          // [27][64]   conv1 weights transposed
  WT2 = 1728,       // [576][64]
  WT3 = 38592,      // [576][64]
  T1  = 75456,      // [9216][64] conv1 out; later reused for bf16 weight frags
  T2  = 665280,     // [9216][64] conv2 out
  FEAT= 1255104,    // [9216][64] conv3 out
  PREDP=1844928,    // [3][147456] pre-refine pred planes
  FLAGP=2287296,    // [147456]
  WS_END = 2434752  // 9.74 MB
};
// bf16 MFMA weight fragments, u16 offsets relative to (u16*)(ws + T1)
// layout per layer: [nt][kt][lane][8]
enum : int { HB1o = 0, HB2o = 24576, HB3o = 90112, HB4o = 155648, HB_TOT = 159744 };

#define QTOT 147456
#define QB   128      // queries per mlp block
#define NBLK 1152

__device__ __forceinline__ u16 f2b(float f){
  union { float f; unsigned int i; } v; v.f = f;
  unsigned int x = v.i;
  x += 0x7fffu + ((x >> 16) & 1u);   // RNE
  return (u16)(x >> 16);
}
__device__ __forceinline__ unsigned cvtpk(float lo, float hi){
  unsigned r; asm("v_cvt_pk_bf16_f32 %0, %1, %2" : "=v"(r) : "v"(lo), "v"(hi)); return r;
}
union Frag { uint4 u; bf16x8 h; };
__device__ __forceinline__ f32x4 MF(bf16x8 a, bf16x8 b, f32x4 c){
  return __builtin_amdgcn_mfma_f32_16x16x32_bf16(a, b, c, 0, 0, 0);
}

// ---------- prep: conv weight transpose ----------
__global__ __launch_bounds__(256) void prep_k(
    const float* __restrict__ ew1, const float* __restrict__ ew2,
    const float* __restrict__ ew3, float* __restrict__ ws)
{
  int t = blockIdx.x * 256 + threadIdx.x;
  if (t < 1728){ int co=t/27,  r=t-co*27;  ws[WT1 + r*64 + co] = ew1[t]; return; } t -= 1728;
  if (t < 36864){ int co=t/576, r=t-co*576; ws[WT2 + r*64 + co] = ew2[t]; return; } t -= 36864;
  if (t < 36864){ int co=t/576, r=t-co*576; ws[WT3 + r*64 + co] = ew3[t]; return; }
}

// ---------- prep_b: heavy-MLP weights -> bf16 MFMA fragment layout ----------
// frag element (nt,kt,lane,i): k = kt*32 + (lane>>4)*8 + i ; n = nt*16 + (lane&15)
__global__ __launch_bounds__(256) void prep_b(
    const float* __restrict__ wh1, const float* __restrict__ wh2,
    const float* __restrict__ wh3, const float* __restrict__ wh4,
    u16* __restrict__ hb)
{
  int t = blockIdx.x * 256 + threadIdx.x;
  if (t < 24576){   // HB1: 16 nt x 3 kt (K=68 padded to 96)
    int i = t&7, lane = (t>>3)&63, g = t>>9, kt = g%3, nt = g/3;
    int k = kt*32 + (lane>>4)*8 + i, n = nt*16 + (lane&15);
    hb[HB1o + t] = f2b(k < 68 ? wh1[k*256 + n] : 0.f); return;
  } t -= 24576;
  if (t < 65536){   // HB2: 16 nt x 8 kt
    int i = t&7, lane = (t>>3)&63, g = t>>9, kt = g&7, nt = g>>3;
    int k = kt*32 + (lane>>4)*8 + i, n = nt*16 + (lane&15);
    hb[HB2o + t] = f2b(wh2[k*256 + n]); return;
  } t -= 65536;
  if (t < 65536){   // HB3
    int i = t&7, lane = (t>>3)&63, g = t>>9, kt = g&7, nt = g>>3;
    int k = kt*32 + (lane>>4)*8 + i, n = nt*16 + (lane&15);
    hb[HB3o + t] = f2b(wh3[k*256 + n]); return;
  } t -= 65536;
  if (t < 4096){    // HB4: 1 nt (N=3 padded to 16) x 8 kt
    int i = t&7, lane = (t>>3)&63, kt = t>>9;
    int k = kt*32 + (lane>>4)*8 + i, n = lane&15;
    hb[HB4o + t] = f2b(n < 3 ? wh4[k*3 + n] : 0.f); return;
  }
}

// ---------- conv1: 3 -> 64, relu ----------
__global__ __launch_bounds__(256) void conv1_k(const float* __restrict__ lr, const float* __restrict__ wt1,
                                               const float* __restrict__ b1, float* __restrict__ out)
{
  int t  = threadIdx.x;
  int px = blockIdx.x * 4 + (t >> 6);
  int co = t & 63;
  int y = px / 96, x = px - y * 96;
  float acc = b1[co];
  #pragma unroll
  for (int dy = -1; dy <= 1; ++dy){
    int ny = y + dy; if (ny < 0 || ny > 95) continue;
    #pragma unroll
    for (int dx = -1; dx <= 1; ++dx){
      int nx = x + dx; if (nx < 0 || nx > 95) continue;
      int tap = (dy+1)*3 + (dx+1);
      #pragma unroll
      for (int ci = 0; ci < 3; ++ci)
        acc += lr[ci*9216 + ny*96 + nx] * wt1[(ci*9 + tap)*64 + co];
    }
  }
  out[px*64 + co] = fmaxf(acc, 0.f);
}

// ---------- conv 64->64 ----------
__global__ __launch_bounds__(256) void conv64_k(const float* __restrict__ in, const float* __restrict__ wt,
                                                const float* __restrict__ bias, float* __restrict__ out, int relu)
{
  int t  = threadIdx.x;
  int px = blockIdx.x * 16 + (t >> 4);
  int co = (t & 15) * 4;
  int y = px / 96, x = px - y * 96;
  float4 acc = *(const float4*)(bias + co);
  #pragma unroll
  for (int dy = -1; dy <= 1; ++dy){
    int ny = y + dy; if (ny < 0 || ny > 95) continue;
    #pragma unroll
    for (int dx = -1; dx <= 1; ++dx){
      int nx = x + dx; if (nx < 0 || nx > 95) continue;
      int tap = (dy+1)*3 + (dx+1);
      const float* ip = in + (ny*96 + nx)*64;
      const float* wp = wt + tap*64 + co;
      #pragma unroll 4
      for (int c4 = 0; c4 < 16; ++c4){
        float4 iv = *(const float4*)(ip + c4*4);
        float4 w0 = *(const float4*)(wp + (c4*4+0)*576);
        float4 w1 = *(const float4*)(wp + (c4*4+1)*576);
        float4 w2 = *(const float4*)(wp + (c4*4+2)*576);
        float4 w3 = *(const float4*)(wp + (c4*4+3)*576);
        acc.x += iv.x*w0.x + iv.y*w1.x + iv.z*w2.x + iv.w*w3.x;
        acc.y += iv.x*w0.y + iv.y*w1.y + iv.z*w2.y + iv.w*w3.y;
        acc.z += iv.x*w0.z + iv.y*w1.z + iv.z*w2.z + iv.w*w3.z;
        acc.w += iv.x*w0.w + iv.y*w1.w + iv.z*w2.w + iv.w*w3.w;
      }
    }
  }
  if (relu){
    acc.x = fmaxf(acc.x, 0.f); acc.y = fmaxf(acc.y, 0.f);
    acc.z = fmaxf(acc.z, 0.f); acc.w = fmaxf(acc.w, 0.f);
  }
  *(float4*)(out + px*64 + co) = acc;
}

// ---------- heavy MFMA layer: acc(n-tile pair x 2 m-tiles), relu, bf16 write to swizzled H ----------
template<int KT>
__device__ __forceinline__ void heavy_layer(const Frag bf[2][KT], const uint4* __restrict__ W,
                                            const float* __restrict__ bias, char* Hb,
                                            int wid, int lrow, int lkg, int lane)
{
  #pragma unroll
  for (int ntp = 0; ntp < 8; ++ntp){
    int na = ntp*2, nb = na+1;
    float4 b0 = *(const float4*)(bias + na*16 + lkg*4);
    float4 b1 = *(const float4*)(bias + nb*16 + lkg*4);
    f32x4 acc[2][2];
    acc[0][0] = f32x4{b0.x, b0.y, b0.z, b0.w}; acc[0][1] = acc[0][0];
    acc[1][0] = f32x4{b1.x, b1.y, b1.z, b1.w}; acc[1][1] = acc[1][0];
    #pragma unroll
    for (int kt = 0; kt < KT; ++kt){
      Frag wa, wb;
      wa.u = W[(na*KT + kt)*64 + lane];
      wb.u = W[(nb*KT + kt)*64 + lane];
      acc[0][0] = MF(wa.h, bf[0][kt].h, acc[0][0]);
      acc[0][1] = MF(wa.h, bf[1][kt].h, acc[0][1]);
      acc[1][0] = MF(wb.h, bf[0][kt].h, acc[1][0]);
      acc[1][1] = MF(wb.h, bf[1][kt].h, acc[1][1]);
    }
    #pragma unroll
    for (int x = 0; x < 2; ++x)
      #pragma unroll
      for (int mt = 0; mt < 2; ++mt){
        int m = wid*32 + mt*16 + lrow;
        int nbase = (na+x)*16 + lkg*4;
        f32x4 v = acc[x][mt];
        uint2 hw = make_uint2(cvtpk(fmaxf(v[0],0.f), fmaxf(v[1],0.f)),
                              cvtpk(fmaxf(v[2],0.f), fmaxf(v[3],0.f)));
        *(uint2*)(Hb + ((m*512 + nbase*2) ^ ((m&7)<<4))) = hw;
      }
  }
}

// ---------- fused per-128-query MLP ----------
// LDS: inpf 38912 + Hs 65536 + fl 512 + plv/gsv 3072 = ~108 KB -> 1 block/CU
__global__ __launch_bounds__(256, 1) void mlp_k(float* __restrict__ ws,
    const float* __restrict__ lr, const float* __restrict__ coord, const float* __restrict__ cell,
    const float* __restrict__ bh1, const float* __restrict__ bh2,
    const float* __restrict__ bh3, const float* __restrict__ bh4,
    const float* __restrict__ wl1, const float* __restrict__ bl1,
    const float* __restrict__ wl2, const float* __restrict__ bl2,
    const float* __restrict__ wc1, const float* __restrict__ bc1,
    const float* __restrict__ wc2, const float* __restrict__ bc2,
    float* __restrict__ dout)
{
  __shared__ float inpf[QB][76];     // stride 76 f32 -> 304B rows, banks spread
  __shared__ u16   Hs[QB*256];       // heavy activations, XOR-swizzled rows
  __shared__ float fl[QB];
  __shared__ float plv[QB*3];
  __shared__ float gsv[QB*3];

  const float* feat = ws + FEAT;
  const u16* HB = (const u16*)(ws + T1);
  const int t = threadIdx.x;
  const int q0 = blockIdx.x * QB;
  const int lane = t & 63, wid = t >> 6;
  const int lrow = lane & 15, lkg = lane >> 4;

  // ---- gather: inpf[128][0..67] ----
  {
    int q = t >> 1, part = t & 1, gq = q0 + q;
    float cy = coord[gq*2+0], cx = coord[gq*2+1];
    int iy = (int)floorf((cy + 1.f) * 0.5f * 96.f); iy = iy < 0 ? 0 : (iy > 95 ? 95 : iy);
    int ix = (int)floorf((cx + 1.f) * 0.5f * 96.f); ix = ix < 0 ? 0 : (ix > 95 ? 95 : ix);
    const float* fp = feat + (iy*96 + ix)*64 + part*32;
    #pragma unroll
    for (int s = 0; s < 8; ++s)
      *(float4*)&inpf[q][part*32 + s*4] = *(const float4*)(fp + s*4);
    if (part == 0){
      float fy = -1.f + (2.f*(float)iy + 1.f) / 96.f;
      float fx = -1.f + (2.f*(float)ix + 1.f) / 96.f;
      inpf[q][64] = (cy - fy) * 96.f;
      inpf[q][65] = (cx - fx) * 96.f;
      inpf[q][66] = cell[gq*2 + 0] * 96.f;
      inpf[q][67] = cell[gq*2 + 1] * 96.f;
    }
  }
  __syncthreads();   // the only barrier

  // ---- classifier (f32 exact; hidden in regs, shfl reduce) ----
  {
    int q = t >> 1, p = t & 1, j0 = p*32;
    float a[32];
    #pragma unroll
    for (int j = 0; j < 32; ++j) a[j] = bc1[j0 + j];
    for (int k = 0; k < 68; ++k){
      float xv = inpf[q][k];
      #pragma unroll
      for (int j = 0; j < 32; ++j) a[j] += xv * wc1[k*64 + j0 + j];
    }
    float l0 = p ? 0.f : bc2[0], l1 = p ? 0.f : bc2[1];
    #pragma unroll
    for (int j = 0; j < 32; ++j){
      float v = fmaxf(a[j], 0.f);
      l0 += v * wc2[(j0+j)*2]; l1 += v * wc2[(j0+j)*2 + 1];
    }
    l0 += __shfl_xor(l0, 1); l1 += __shfl_xor(l1, 1);
    if (p == 0){
      float f = (l1 > l0) ? 1.f : 0.f;
      fl[q] = f; ws[FLAGP + q0 + q] = f; dout[3*QTOT + q0 + q] = f;
    }
  }

  // ---- light MLP + grid sample ----
  {
    int q = t >> 1, p = t & 1, j0 = p*32;
    float a[32];
    #pragma unroll
    for (int j = 0; j < 32; ++j) a[j] = bl1[j0 + j];
    for (int k = 0; k < 68; ++k){
      float xv = inpf[q][k];
      #pragma unroll
      for (int j = 0; j < 32; ++j) a[j] += xv * wl1[k*64 + j0 + j];
    }
    float o0 = p ? 0.f : bl2[0], o1 = p ? 0.f : bl2[1], o2 = p ? 0.f : bl2[2];
    #pragma unroll
    for (int j = 0; j < 32; ++j){
      float v = fmaxf(a[j], 0.f);
      o0 += v*wl2[(j0+j)*3]; o1 += v*wl2[(j0+j)*3+1]; o2 += v*wl2[(j0+j)*3+2];
    }
    o0 += __shfl_xor(o0, 1); o1 += __shfl_xor(o1, 1); o2 += __shfl_xor(o2, 1);
    if (p == 0){
      int gq = q0 + q;
      float cy = coord[gq*2], cx = coord[gq*2 + 1];
      float fy = fminf(fmaxf((cy + 1.f) * 96.f / 2.f - 0.5f, 0.f), 95.f);
      float fx = fminf(fmaxf((cx + 1.f) * 96.f / 2.f - 0.5f, 0.f), 95.f);
      float y0f = floorf(fy), x0f = floorf(fx);
      float wy = fy - y0f, wx = fx - x0f;
      int y0 = (int)y0f, x0 = (int)x0f;
      int y1 = y0 + 1 > 95 ? 95 : y0 + 1;
      int x1 = x0 + 1 > 95 ? 95 : x0 + 1;
      float oo[3] = {o0, o1, o2};
      #pragma unroll
      for (int c = 0; c < 3; ++c){
        const float* lp = lr + c*9216;
        float v = lp[y0*96+x0]*(1.f-wy)*(1.f-wx) + lp[y0*96+x1]*(1.f-wy)*wx
                + lp[y1*96+x0]*wy*(1.f-wx) + lp[y1*96+x1]*wy*wx;
        gsv[q*3 + c] = v; plv[q*3 + c] = oo[c] + v;
      }
    }
  }
  // no further barriers: each wave only touches its own 32 rows from here on

  char* Hb = (char*)Hs;

  // ---- heavy layer 1: inpf -> H  (K=68 padded: kt0/1 = feat, kt2 = rel/cell + zeros) ----
  {
    Frag bf[2][3];
    #pragma unroll
    for (int mt = 0; mt < 2; ++mt){
      int m = wid*32 + mt*16 + lrow;
      #pragma unroll
      for (int kt = 0; kt < 2; ++kt){
        float4 lo = *(const float4*)&inpf[m][kt*32 + lkg*8];
        float4 hi = *(const float4*)&inpf[m][kt*32 + lkg*8 + 4];
        bf[mt][kt].u = make_uint4(cvtpk(lo.x,lo.y), cvtpk(lo.z,lo.w),
                                  cvtpk(hi.x,hi.y), cvtpk(hi.z,hi.w));
      }
      uint4 z = make_uint4(0,0,0,0);
      if (lkg == 0){
        float4 rc = *(const float4*)&inpf[m][64];
        z.x = cvtpk(rc.x, rc.y); z.y = cvtpk(rc.z, rc.w);
      }
      bf[mt][2].u = z;
    }
    heavy_layer<3>(bf, (const uint4*)(HB + HB1o), bh1, Hb, wid, lrow, lkg, lane);
  }

  // ---- heavy layer 2: H -> H (in place; B-frags fully preloaded) ----
  {
    Frag bf[2][8];
    #pragma unroll
    for (int mt = 0; mt < 2; ++mt){
      int m = wid*32 + mt*16 + lrow;
      #pragma unroll
      for (int kt = 0; kt < 8; ++kt)
        bf[mt][kt].u = *(const uint4*)(Hb + ((m*512 + kt*64 + lkg*16) ^ ((m&7)<<4)));
    }
    heavy_layer<8>(bf, (const uint4*)(HB + HB2o), bh2, Hb, wid, lrow, lkg, lane);
  }

  // ---- heavy layer 3 ----
  {
    Frag bf[2][8];
    #pragma unroll
    for (int mt = 0; mt < 2; ++mt){
      int m = wid*32 + mt*16 + lrow;
      #pragma unroll
      for (int kt = 0; kt < 8; ++kt)
        bf[mt][kt].u = *(const uint4*)(Hb + ((m*512 + kt*64 + lkg*16) ^ ((m&7)<<4)));
    }
    heavy_layer<8>(bf, (const uint4*)(HB + HB3o), bh3, Hb, wid, lrow, lkg, lane);
  }

  // ---- heavy layer 4 (256 -> 3, padded to 16) + select + store ----
  {
    Frag bf[2][8];
    #pragma unroll
    for (int mt = 0; mt < 2; ++mt){
      int m = wid*32 + mt*16 + lrow;
      #pragma unroll
      for (int kt = 0; kt < 8; ++kt)
        bf[mt][kt].u = *(const uint4*)(Hb + ((m*512 + kt*64 + lkg*16) ^ ((m&7)<<4)));
    }
    const uint4* W4 = (const uint4*)(HB + HB4o);
    f32x4 a4[2];
    a4[0] = f32x4{0.f,0.f,0.f,0.f}; a4[1] = a4[0];
    #pragma unroll
    for (int kt = 0; kt < 8; ++kt){
      Frag w; w.u = W4[kt*64 + lane];
      a4[0] = MF(w.h, bf[0][kt].h, a4[0]);
      a4[1] = MF(w.h, bf[1][kt].h, a4[1]);
    }
    if (lkg == 0){   // lanes 0-15 hold rows n=0..3 (only 0..2 real)
      #pragma unroll
      for (int mt = 0; mt < 2; ++mt){
        int m = wid*32 + mt*16 + lrow, gq = q0 + m;
        bool hard = fl[m] > 0.5f;
        #pragma unroll
        for (int r = 0; r < 3; ++r){
          float pv = hard ? (a4[mt][r] + bh4[r] + gsv[m*3 + r]) : plv[m*3 + r];
          ws[PREDP + r*QTOT + gq] = pv;
        }
      }
    }
  }
}

// ---------- refinement + f32 store ----------
__global__ __launch_bounds__(256) void refine_k(const float* __restrict__ ws, float* __restrict__ dout)
{
  int q = blockIdx.x * 256 + threadIdx.x;
  const float* predp = ws + PREDP;
  const float* flagp = ws + FLAGP;
  int y = q / 384, x = q - y*384;
  float p0 = predp[q], p1 = predp[QTOT + q], p2 = predp[2*QTOT + q];
  if (y > 0 && y < 383 && x > 0 && x < 383 && flagp[q] == 0.f){
    float fs = 0.f, s0 = 0.f, s1 = 0.f, s2 = 0.f;
    #pragma unroll
    for (int dy = -1; dy <= 1; ++dy){
      #pragma unroll
      for (int dx = -1; dx <= 1; ++dx){
        int nq = q + dy*384 + dx;
        fs += flagp[nq];
        s0 += predp[nq]; s1 += predp[QTOT + nq]; s2 += predp[2*QTOT + nq];
      }
    }
    if (fs > 0.5f){ p0 = s0 / 9.f; p1 = s1 / 9.f; p2 = s2 / 9.f; }
  }
  dout[q*3 + 0] = p0;
  dout[q*3 + 1] = p1;
  dout[q*3 + 2] = p2;
}

extern "C" void kernel_launch(void* const* d_in, const int* in_sizes, int n_in,
                              void* d_out, int out_size, void* d_ws, size_t ws_size,
                              hipStream_t stream)
{
  const float* lr    = (const float*)d_in[0];
  const float* coord = (const float*)d_in[1];
  const float* cell  = (const float*)d_in[2];
  const float* ew1 = (const float*)d_in[3];  const float* eb1 = (const float*)d_in[4];
  const float* ew2 = (const float*)d_in[5];  const float* eb2 = (const float*)d_in[6];
  const float* ew3 = (const float*)d_in[7];  const float* eb3 = (const float*)d_in[8];
  const float* wh1 = (const float*)d_in[9];  const float* bh1 = (const float*)d_in[10];
  const float* wh2 = (const float*)d_in[11]; const float* bh2 = (const float*)d_in[12];
  const float* wh3 = (const float*)d_in[13]; const float* bh3 = (const float*)d_in[14];
  const float* wh4 = (const float*)d_in[15]; const float* bh4 = (const float*)d_in[16];
  const float* wl1 = (const float*)d_in[17]; const float* bl1 = (const float*)d_in[18];
  const float* wl2 = (const float*)d_in[19]; const float* bl2 = (const float*)d_in[20];
  const float* wc1 = (const float*)d_in[21]; const float* bc1 = (const float*)d_in[22];
  const float* wc2 = (const float*)d_in[23]; const float* bc2 = (const float*)d_in[24];
  float* ws  = (float*)d_ws;
  float* out = (float*)d_out;

  prep_k<<<295, 256, 0, stream>>>(ew1, ew2, ew3, ws);
  conv1_k<<<2304, 256, 0, stream>>>(lr, ws + WT1, eb1, ws + T1);
  conv64_k<<<576, 256, 0, stream>>>(ws + T1, ws + WT2, eb2, ws + T2, 1);
  // T1 now dead -> pack heavy weights into it as bf16 fragments
  prep_b<<<624, 256, 0, stream>>>(wh1, wh2, wh3, wh4, (u16*)(ws + T1));
  conv64_k<<<576, 256, 0, stream>>>(ws + T2, ws + WT3, eb3, ws + FEAT, 0);
  mlp_k<<<NBLK, 256, 0, stream>>>(ws, lr, coord, cell,
                                  bh1, bh2, bh3, bh4,
                                  wl1, bl1, wl2, bl2, wc1, bc1, wc2, bc2, out);
  refine_k<<<576, 256, 0, stream>>>(ws, out);
}